// Round 10
// baseline (234.775 us; speedup 1.0000x reference)
//
#include <hip/hip_runtime.h>

// CapsNet dynamic routing, MI355X. Never materialize u_hat.
// R10: launch-count attack (13 -> 9). softmax fused into s_pass (per-block online-softmax stats
//      recompute, c applied at staging); pack_w+pack_x merged. redsq/agree bodies R9-verbatim.

typedef __attribute__((ext_vector_type(8))) __bf16 bf16x8;
typedef __attribute__((ext_vector_type(4))) float  f32x4;
typedef __attribute__((ext_vector_type(8))) unsigned short u16x8;
typedef __attribute__((ext_vector_type(4))) unsigned int  u32x4;

#define DI __device__ __forceinline__

DI float bf2f(unsigned short u){ unsigned int x = ((unsigned int)u) << 16; return __builtin_bit_cast(float, x); }
DI unsigned short f2bf(float f){
  unsigned int u = __builtin_bit_cast(unsigned int, f);
  u += 0x7fffu + ((u >> 16) & 1u);            // round-to-nearest-even
  return (unsigned short)(u >> 16);
}
DI unsigned int cvtpk(float lo, float hi){    // packed RNE f32->bf16 pair
  unsigned int r;
  asm("v_cvt_pk_bf16_f32 %0, %1, %2" : "=v"(r) : "v"(lo), "v"(hi));
  return r;
}

constexpr int Ci = 4096, Kk = 32, Jj = 10, Dd = 16, Bb = 128;
constexpr int KI = Ci * Kk;    // 131072 flattened (k,i), ki = k*4096 + i
constexpr int JDt = Jj * Dd;   // 160, jd = j*16 + d
constexpr int NCH = 256, CK = 512;  // s-pass split-K chunks

// workspace layout (bytes)
constexpr size_t OFF_XB = 0;
constexpr size_t SZ_XB  = (size_t)Bb * KI * 2;        // 33,554,432  xbf[b][ki]
constexpr size_t OFF_W2 = OFF_XB + SZ_XB;
constexpr size_t SZ_W2  = (size_t)JDt * KI * 2;       // 41,943,040  w2[m][i], m=jd*32+k
constexpr size_t OFF_BT = OFF_W2 + SZ_W2;
constexpr size_t SZ_BT  = (size_t)Jj * Ci * 4;        // 163,840  bT[j][i]
constexpr size_t OFF_VBT = OFF_BT + SZ_BT;
constexpr size_t SZ_VBT = (size_t)JDt * Bb * 2;       // vbT[jd][b]
constexpr size_t OFF_SP = OFF_VBT + SZ_VBT;
constexpr size_t SZ_SP  = (size_t)NCH * Bb * JDt * 4; // 20,971,520  spart[ch][b][jd]

// ---- merged pack: blocks [0,640) pack_w; [640,4736) pack_x; [4736,4756) zero bT ----
constexpr int WPAD = 522;
__global__ __launch_bounds__(512) void pack_all(const float* __restrict__ x, const float* __restrict__ W,
                                                unsigned short* __restrict__ xbf, unsigned short* __restrict__ w2,
                                                float* __restrict__ bT){
  __shared__ unsigned short t16[64 * WPAD];           // 66,816 B (reserved by all branches)
  const int bid = blockIdx.x;
  if(bid < 640){
    // pack W: f32 W[i][m] (row 5120) -> bf16 w2[m][i]; [64 i x 512 m] tiles, 2KB contiguous reads
    const int mt = bid % 10, it = bid / 10;
    const int m0 = mt * 512, i0 = it * 64;
    #pragma unroll
    for(int u=0; u<16; u++){
      int e = threadIdx.x + 512*u;
      int row = e >> 7, c4 = e & 127;
      float4 v = *(const float4*)(W + (size_t)(i0+row)*5120 + m0 + c4*4);
      unsigned int* p = (unsigned int*)(t16 + row*WPAD + c4*4);
      p[0] = cvtpk(v.x, v.y);
      p[1] = cvtpk(v.z, v.w);
    }
    __syncthreads();
    #pragma unroll
    for(int u=0; u<8; u++){
      int e = threadIdx.x + 512*u;
      int mr = e >> 3, g = e & 7;
      u32x4 o;
      #pragma unroll
      for(int j=0; j<4; j++){
        unsigned int lo = t16[(g*8 + 2*j    )*WPAD + mr];
        unsigned int hi = t16[(g*8 + 2*j + 1)*WPAD + mr];
        o[j] = lo | (hi << 16);
      }
      *(u32x4*)(w2 + (size_t)(m0+mr)*Ci + i0 + g*8) = o;
    }
  } else if(bid < 4736){
    // pack x: linear f32 -> bf16 cast, 8 elems/thread
    const size_t e = (size_t)(bid - 640) * 512 + threadIdx.x;
    const float4* xv = (const float4*)x;
    float4 a = xv[e*2], b = xv[e*2+1];
    u32x4 o;
    o[0]=cvtpk(a.x,a.y); o[1]=cvtpk(a.z,a.w);
    o[2]=cvtpk(b.x,b.y); o[3]=cvtpk(b.z,b.w);
    *(u32x4*)(xbf + e*8) = o;
  } else {
    // zero bT: 20 blocks x 512 threads x 16B
    ((f32x4*)bT)[(size_t)(bid-4736)*512 + threadIdx.x] = f32x4{0.f,0.f,0.f,0.f};
  }
}

// ---- s-pass with fused softmax: stats (online m,s per j) + c applied at staging ----
__global__ __launch_bounds__(512) void s_pass(const unsigned short* __restrict__ xb,
                                              const unsigned short* __restrict__ w2,
                                              const float* __restrict__ bT,   // nullptr at t=0
                                              float* __restrict__ spart){
  __shared__ unsigned short xs[128*64];    // [b][k] rows 128B, XOR-swizzled
  __shared__ unsigned short wsm[160*64];   // [jd][k] rows 128B, XOR-swizzled, pre-scaled by c
  __shared__ float jmx[Jj], jinv[Jj];
  const int tid = threadIdx.x, lane = tid & 63, wid = tid >> 6;
  const int wb = wid & 3, wj = wid >> 2;
  const int ki0 = blockIdx.x * CK;

  // softmax stats: wave wid handles j = wid (+8); single-pass online (m,s); c = exp(b-m)/s
  if(bT){
    for(int j = wid; j < Jj; j += 8){
      float m = -3.4e38f, s = 0.f;
      const float* row = bT + j*Ci;
      #pragma unroll
      for(int c0 = 0; c0 < 8; ++c0){               // lane covers 64 elems in 8 chunks of 8
        const float* p = row + lane*8 + c0*512;
        f32x4 a = *(const f32x4*)p;
        f32x4 b = *(const f32x4*)(p+4);
        #pragma unroll
        for(int q=0;q<4;q++){ float v=a[q]; float m2=fmaxf(m,v); s = s*__expf(m-m2)+__expf(v-m2); m=m2; }
        #pragma unroll
        for(int q=0;q<4;q++){ float v=b[q]; float m2=fmaxf(m,v); s = s*__expf(m-m2)+__expf(v-m2); m=m2; }
      }
      #pragma unroll
      for(int o=32;o>0;o>>=1){
        float mo = __shfl_xor(m,o), so = __shfl_xor(s,o);
        float m2 = fmaxf(m, mo);
        s = s*__expf(m-m2) + so*__expf(mo-m2);
        m = m2;
      }
      if(lane==0){ jmx[j] = m; jinv[j] = 1.0f / s; }
    }
  }
  __syncthreads();

  f32x4 acc[2][5];
  const f32x4 z = {0.f,0.f,0.f,0.f};
  #pragma unroll
  for(int m=0;m<2;m++){ acc[m][0]=z; acc[m][1]=z; acc[m][2]=z; acc[m][3]=z; acc[m][4]=z; }

  for(int step=0; step<CK/64; ++step){
    const int kb = ki0 + step*64;
    const int ib = kb & (Ci-1);       // chunk stays inside one k-slab, i base
    #pragma unroll
    for(int u=0; u<2; u++){           // stage x tile [128 b][64 ki]
      int e = tid + 512*u;
      int b = e >> 3, sg = e & 7;
      u16x8 v = *(const u16x8*)(xb + (size_t)b*KI + kb + sg*8);
      *(u16x8*)((char*)xs + b*128 + ((sg*16) ^ ((b&7)<<4))) = v;
    }
    #pragma unroll
    for(int u=0; u<3; u++){           // stage w tile [160 jd][64 ki] * c[i][j]
      int e = tid + 512*u;
      if(e < 1280){
        int jd = e >> 3, sg = e & 7;
        u16x8 v = *(const u16x8*)(w2 + (size_t)jd*KI + kb + sg*8);
        float cc[8];
        if(bT){
          const int j = jd >> 4;
          const float* bp = bT + j*Ci + ib + sg*8;
          f32x4 b0 = *(const f32x4*)bp;
          f32x4 b1 = *(const f32x4*)(bp+4);
          const float mxj = jmx[j], ivj = jinv[j];
          cc[0]=__expf(b0[0]-mxj)*ivj; cc[1]=__expf(b0[1]-mxj)*ivj;
          cc[2]=__expf(b0[2]-mxj)*ivj; cc[3]=__expf(b0[3]-mxj)*ivj;
          cc[4]=__expf(b1[0]-mxj)*ivj; cc[5]=__expf(b1[1]-mxj)*ivj;
          cc[6]=__expf(b1[2]-mxj)*ivj; cc[7]=__expf(b1[3]-mxj)*ivj;
        } else {
          #pragma unroll
          for(int q=0;q<8;q++) cc[q] = (1.0f/4096.0f);
        }
        u16x8 o;
        #pragma unroll
        for(int q=0;q<8;q++) o[q] = f2bf(bf2f(v[q])*cc[q]);
        *(u16x8*)((char*)wsm + jd*128 + ((sg*16) ^ ((jd&7)<<4))) = o;
      }
    }
    __syncthreads();
    #pragma unroll
    for(int ks=0; ks<2; ks++){
      const int kk2 = (ks*32 + ((lane>>4)<<3)) * 2;   // byte offset of 8-k group
      bf16x8 a[2];
      #pragma unroll
      for(int m=0;m<2;m++){
        int row = wb*32 + m*16 + (lane&15);
        a[m] = *(const bf16x8*)((const char*)xs + row*128 + (kk2 ^ ((row&7)<<4)));
      }
      #pragma unroll
      for(int n=0;n<5;n++){
        int row = wj*80 + n*16 + (lane&15);
        bf16x8 bb = *(const bf16x8*)((const char*)wsm + row*128 + (kk2 ^ ((row&7)<<4)));
        acc[0][n] = __builtin_amdgcn_mfma_f32_16x16x32_bf16(a[0], bb, acc[0][n], 0,0,0);
        acc[1][n] = __builtin_amdgcn_mfma_f32_16x16x32_bf16(a[1], bb, acc[1][n], 0,0,0);
      }
    }
    __syncthreads();
  }
  float* sp = spart + (size_t)blockIdx.x * (Bb*JDt);
  #pragma unroll
  for(int m=0;m<2;m++)
    #pragma unroll
    for(int n=0;n<5;n++)
      #pragma unroll
      for(int r=0;r<4;r++){
        int b  = wb*32 + m*16 + ((lane>>4)<<2) + r;     // D-frag: row=(lane>>4)*4+r
        int jd = wj*80 + n*16 + (lane&15);              //          col=lane&15
        sp[b*JDt + jd] = acc[m][n][r];
      }
}

// ---- reduce split-K partials + squash (R9 verbatim) ----
__global__ __launch_bounds__(256) void redsq(const float* __restrict__ spart,
                                             float* __restrict__ vout,
                                             unsigned short* __restrict__ vbT){
  const int b = blockIdx.x, tid = threadIdx.x;
  __shared__ float sq[JDt];
  __shared__ float scale[Dd];
  float s = 0.f;
  if(tid < JDt){
    const float* p = spart + b*JDt + tid;
    #pragma unroll 8
    for(int ch=0; ch<NCH; ch++) s += p[(size_t)ch*(Bb*JDt)];
    sq[tid] = s*s;
  }
  __syncthreads();
  if(tid < Dd){
    float m = 0.f;
    #pragma unroll
    for(int j=0;j<Jj;j++) m += sq[j*Dd + tid];
    scale[tid] = sqrtf(m) / (1.0f + m);    // v = s * sqrt(m)/(1+m)
  }
  __syncthreads();
  if(tid < JDt){
    float v = s * scale[tid & (Dd-1)];
    vout[b*JDt + tid] = v;
    vbT[tid*Bb + b] = f2bf(v);
  }
}

// ---- agree pass (R9 verbatim): LDS-staged, epilogue dots W2, atomicAdd -> bT ----
__global__ __launch_bounds__(256) void agree_pass(const unsigned short* __restrict__ xb,
                                                  const unsigned short* __restrict__ vbT,
                                                  const unsigned short* __restrict__ w2,
                                                  float* __restrict__ bT){
  __shared__ unsigned short xsT[64*128];   // [ki][b] rows 256B, swizzled (16 KB)
  __shared__ unsigned short vsm[160*128];  // [jd][b] rows 256B, swizzled (40 KB)
  const int tid = threadIdx.x, lane = tid & 63, wid = tid >> 6;
  const int wj = wid & 1, wk = wid >> 1;
  const int ki0 = blockIdx.x * 64;
  #pragma unroll
  for(int u=0; u<4; u++){                  // stage x transposed
    int e = tid + 256*u;
    int b = e >> 3, sg = e & 7;
    u16x8 v = *(const u16x8*)(xb + (size_t)b*KI + ki0 + sg*8);
    #pragma unroll
    for(int q=0; q<8; q++){
      int kil = sg*8 + q;
      *(unsigned short*)((char*)xsT + kil*256 + ((b*2) ^ ((kil&7)<<4))) = v[q];
    }
  }
  #pragma unroll
  for(int u=0; u<10; u++){                 // stage v
    int e = tid + 256*u;
    int jd = e >> 4, sg = e & 15;
    u16x8 v = *(const u16x8*)(vbT + jd*Bb + sg*8);
    *(u16x8*)((char*)vsm + jd*256 + ((sg*16) ^ ((jd&7)<<4))) = v;
  }
  __syncthreads();
  f32x4 acc[5][2];
  const f32x4 z = {0.f,0.f,0.f,0.f};
  #pragma unroll
  for(int m=0;m<5;m++){ acc[m][0]=z; acc[m][1]=z; }
  #pragma unroll
  for(int ks=0; ks<4; ks++){
    const int b2 = (ks*32 + ((lane>>4)<<3)) * 2;
    bf16x8 bfr[2];
    #pragma unroll
    for(int n=0;n<2;n++){
      int row = wk*32 + n*16 + (lane&15);
      bfr[n] = *(const bf16x8*)((const char*)xsT + row*256 + (b2 ^ ((row&7)<<4)));
    }
    #pragma unroll
    for(int m=0;m<5;m++){
      int row = wj*80 + m*16 + (lane&15);
      bf16x8 af = *(const bf16x8*)((const char*)vsm + row*256 + (b2 ^ ((row&7)<<4)));
      acc[m][0] = __builtin_amdgcn_mfma_f32_16x16x32_bf16(af, bfr[0], acc[m][0], 0,0,0);
      acc[m][1] = __builtin_amdgcn_mfma_f32_16x16x32_bf16(af, bfr[1], acc[m][1], 0,0,0);
    }
  }
  const int ibase = ki0 & (Ci-1);
  #pragma unroll
  for(int m=0;m<5;m++){
    int j = wj*5 + m;
    #pragma unroll
    for(int n=0;n<2;n++){
      int colg = ki0 + wk*32 + n*16 + (lane&15);
      float s = 0.f;
      #pragma unroll
      for(int r=0;r<4;r++){
        int jdrow = wj*80 + m*16 + ((lane>>4)<<2) + r;   // = j*16 + d
        s += acc[m][n][r] * bf2f(w2[(size_t)jdrow*KI + colg]);
      }
      s += __shfl_xor(s, 16);      // lanes l and l^16/l^32 share the same column (i)
      s += __shfl_xor(s, 32);
      if(lane < 16){
        int ig = ibase + wk*32 + n*16 + lane;
        atomicAdd(bT + j*Ci + ig, s * (1.0f/128.0f));
      }
    }
  }
}

extern "C" void kernel_launch(void* const* d_in, const int* in_sizes, int n_in,
                              void* d_out, int out_size, void* d_ws, size_t ws_size,
                              hipStream_t stream) {
  const float* x = (const float*)d_in[0];
  const float* W = (const float*)d_in[1];
  float* out = (float*)d_out;
  char* ws = (char*)d_ws;
  unsigned short* xbf = (unsigned short*)(ws + OFF_XB);
  unsigned short* w2  = (unsigned short*)(ws + OFF_W2);
  float* bT           = (float*)(ws + OFF_BT);
  unsigned short* vbT = (unsigned short*)(ws + OFF_VBT);
  float* spart        = (float*)(ws + OFF_SP);

  pack_all<<<4756, 512, 0, stream>>>(x, W, xbf, w2, bT);   // packs + bT zero
  for(int t=0; t<3; t++){
    s_pass<<<NCH, 512, 0, stream>>>(xbf, w2, (t==0)? nullptr : bT, spart);
    redsq<<<Bb, 256, 0, stream>>>(spart, out, vbT);
    if(t < 2) agree_pass<<<KI/64, 256, 0, stream>>>(xbf, vbT, w2, bT);
  }
}